// Round 2
// baseline (210.605 us; speedup 1.0000x reference)
//
#include <hip/hip_runtime.h>
#include <math.h>

// EUNN layer, H=1024: 16 steps of (even + odd) pairwise complex rotations + final phase.
// v2: raw (ct,st,cp,sp) coefficients (16B/pair), software-pipelined coeff loads,
// wide-parallel precompute, nontemporal x/out streaming.
//
// ws layout: f4 coeff[16][1024]  (k<512: even pair k; k>=512: odd pair k-512,
//            entry 1023 of each step = identity ct=1,st=0,cp=0,sp=1)
//            f2 omcs[1024] at float offset 65536  (cos w, sin w)

typedef float f4 __attribute__((ext_vector_type(4)));
typedef float f2 __attribute__((ext_vector_type(2)));

#define OMCS_OFF 65536

__global__ __launch_bounds__(256) void eunn_precompute(
    const float* __restrict__ omega, const float* __restrict__ et,
    const float* __restrict__ ot, const float* __restrict__ ep,
    const float* __restrict__ op, float* __restrict__ ws) {
  int tid = blockIdx.x * 256 + threadIdx.x;
  if (tid < 16384) {
    int s = tid >> 10, k = tid & 1023;
    float ct, st, cp, sp;
    if (k < 512) {
      sincosf(et[s * 512 + k], &st, &ct);
      sincosf(ep[s * 512 + k], &sp, &cp);
    } else {
      int j = k - 512;
      if (j < 511) {
        sincosf(ot[s * 511 + j], &st, &ct);
        sincosf(op[s * 511 + j], &sp, &cp);
      } else {  // identity pad pair (elements 1023/1024)
        ct = 1.f; st = 0.f; cp = 0.f; sp = 1.f;
      }
    }
    ((f4*)ws)[tid] = (f4){ct, st, cp, sp};
  } else if (tid < 17408) {
    int i = tid - 16384;
    float sw, cw;
    sincosf(omega[i], &sw, &cw);
    ((f2*)(ws + OMCS_OFF))[i] = (f2){cw, sw};
  }
}

// One wave owns R rows; lane l owns elements 16l..16l+15 (8 even pairs).
// Even rotations are register-local; odd rotations register-local except one
// boundary pair per lane (intra-wave shfl). Coefficient loads for phase k+1
// are issued before the compute of phase k (1-phase software pipeline).
template <int R>
__global__ __launch_bounds__(256, 2) void eunn_main(
    const float* __restrict__ x, float* __restrict__ out,
    const float* __restrict__ ws) {
  const int lane = threadIdx.x & 63;
  const int wid = blockIdx.x * (blockDim.x >> 6) + (threadIdx.x >> 6);
  const f4* cf = (const f4*)ws;

  // e[r][p] = (re[16l+2p], im[16l+2p], re[16l+2p+1], im[16l+2p+1])
  f4 e[R][8];
#pragma unroll
  for (int r = 0; r < R; ++r) {
    const f4* xr = (const f4*)(x + (size_t)(wid * R + r) * 2048) + lane * 8;
#pragma unroll
    for (int p = 0; p < 8; ++p) e[r][p] = __builtin_nontemporal_load(xr + p);
  }

  f4 E[8];  // current step's even coeffs (ct,st,cp,sp per pair)
  {
    const f4* eb = cf + lane * 8;
#pragma unroll
    for (int p = 0; p < 8; ++p) E[p] = eb[p];
  }

#pragma unroll 2
  for (int s = 0; s < 16; ++s) {
    // ---- issue odd coeff loads (cover with even compute) ----
    f4 O[8];
    {
      const f4* ob = cf + (s * 1024 + 512) + lane * 8;
#pragma unroll
      for (int p = 0; p < 8; ++p) O[p] = ob[p];
    }
    // ---- even rotation: pair j=8l+p couples (e.x,e.y) and (e.z,e.w) ----
#pragma unroll
    for (int r = 0; r < R; ++r) {
#pragma unroll
      for (int p = 0; p < 8; ++p) {
        f4 c = E[p];
        f4 v = e[r][p];
        float t0 = c.x * v.x - c.y * v.z;
        float t1 = c.x * v.y - c.y * v.w;
        e[r][p] = (f4){c.w * t0 - c.z * t1, c.z * t0 + c.w * t1,
                       c.y * v.x + c.x * v.z, c.y * v.y + c.x * v.w};
      }
    }
    // ---- prefetch next step's even coeffs (cover with odd compute) ----
    f4 NE[8];
    {
      const f4* nb = cf + (((s + 1) & 15) * 1024) + lane * 8;
#pragma unroll
      for (int p = 0; p < 8; ++p) NE[p] = nb[p];
    }
    // ---- odd rotation: pair j couples elements 2j+1, 2j+2 ----
    {
      // neighbor pair (8l-1)'s (ct,st) from lane l-1; identity at lane 0
      float ctm = __shfl_up(O[7].x, 1, 64);
      float stm = __shfl_up(O[7].y, 1, 64);
      if (lane == 0) { ctm = 1.f; stm = 0.f; }
#pragma unroll
      for (int r = 0; r < R; ++r) {
        float upx = __shfl_down(e[r][0].x, 1, 64);  // elem 16l+16 (pre)
        float upy = __shfl_down(e[r][0].y, 1, 64);
        float dnz = __shfl_up(e[r][7].z, 1, 64);    // elem 16l-1 (pre)
        float dnw = __shfl_up(e[r][7].w, 1, 64);
        // element 16l = second half of pair 8l-1
        float nx = stm * dnz + ctm * e[r][0].x;
        float ny = stm * dnw + ctm * e[r][0].y;
        e[r][0].x = nx;
        e[r][0].y = ny;
        // interior odd pairs j=8l+p, p=0..6
#pragma unroll
        for (int p = 0; p < 7; ++p) {
          f4 c = O[p];
          float e0r = e[r][p].z, e0i = e[r][p].w;
          float e1r = e[r][p + 1].x, e1i = e[r][p + 1].y;
          float t0 = c.x * e0r - c.y * e1r;
          float t1 = c.x * e0i - c.y * e1i;
          e[r][p].z = c.w * t0 - c.z * t1;
          e[r][p].w = c.z * t0 + c.w * t1;
          e[r][p + 1].x = c.y * e0r + c.x * e1r;
          e[r][p + 1].y = c.y * e0i + c.x * e1i;
        }
        // boundary pair j=8l+7 (second element lives in lane l+1; lane 63 = identity)
        {
          f4 c = O[7];
          float e0r = e[r][7].z, e0i = e[r][7].w;
          float t0 = c.x * e0r - c.y * upx;
          float t1 = c.x * e0i - c.y * upy;
          e[r][7].z = c.w * t0 - c.z * t1;
          e[r][7].w = c.z * t0 + c.w * t1;
        }
      }
    }
#pragma unroll
    for (int p = 0; p < 8; ++p) E[p] = NE[p];
  }

  // ---- final diagonal phase + nontemporal store ----
  const f4* om4 = (const f4*)(ws + OMCS_OFF) + lane * 8;  // (c,s,c,s)
#pragma unroll
  for (int r = 0; r < R; ++r) {
    f4* outr = (f4*)(out + (size_t)(wid * R + r) * 2048) + lane * 8;
#pragma unroll
    for (int p = 0; p < 8; ++p) {
      f4 v = e[r][p];
      f4 w = om4[p];
      f4 o = (f4){v.x * w.x - v.y * w.y, v.x * w.y + v.y * w.x,
                  v.z * w.z - v.w * w.w, v.z * w.w + v.w * w.z};
      __builtin_nontemporal_store(o, outr + p);
    }
  }
}

extern "C" void kernel_launch(void* const* d_in, const int* in_sizes, int n_in,
                              void* d_out, int out_size, void* d_ws, size_t ws_size,
                              hipStream_t stream) {
  const float* x     = (const float*)d_in[0];  // (4096,1024,2)
  const float* omega = (const float*)d_in[1];  // (1024,)
  const float* et    = (const float*)d_in[2];  // (16,512)
  const float* ot    = (const float*)d_in[3];  // (16,511)
  const float* ep    = (const float*)d_in[4];  // (16,512)
  const float* op    = (const float*)d_in[5];  // (16,511)
  float* out = (float*)d_out;
  float* ws  = (float*)d_ws;

  // 17408 jobs: 16x1024 coeff quads + 1024 omega entries
  eunn_precompute<<<dim3(68), dim3(256), 0, stream>>>(omega, et, ot, ep, op, ws);

  // R=2 rows/wave: 2048 waves, 4 waves/block -> 512 blocks
  eunn_main<2><<<dim3(512), dim3(256), 0, stream>>>(x, out, ws);
}

// Round 3
// 158.579 us; speedup vs baseline: 1.3281x; 1.3281x over previous
//
#include <hip/hip_runtime.h>
#include <math.h>

// EUNN layer, H=1024: 16 steps of (even + odd) pairwise complex rotations + final phase.
// v3: v2 pipeline minus the spill — no NE stage array (load next-even directly
// into E after even compute), no s-loop unroll, plain loads/stores.
//
// ws layout: f4 coeff[16][1024]  (k<512: even pair k; k>=512: odd pair k-512,
//            entry 1023 of each step = identity ct=1,st=0,cp=0,sp=1)
//            f2 omcs[1024] at float offset 65536  (cos w, sin w)

typedef float f4 __attribute__((ext_vector_type(4)));
typedef float f2 __attribute__((ext_vector_type(2)));

#define OMCS_OFF 65536

__global__ __launch_bounds__(256) void eunn_precompute(
    const float* __restrict__ omega, const float* __restrict__ et,
    const float* __restrict__ ot, const float* __restrict__ ep,
    const float* __restrict__ op, float* __restrict__ ws) {
  int tid = blockIdx.x * 256 + threadIdx.x;
  if (tid < 16384) {
    int s = tid >> 10, k = tid & 1023;
    float ct, st, cp, sp;
    if (k < 512) {
      sincosf(et[s * 512 + k], &st, &ct);
      sincosf(ep[s * 512 + k], &sp, &cp);
    } else {
      int j = k - 512;
      if (j < 511) {
        sincosf(ot[s * 511 + j], &st, &ct);
        sincosf(op[s * 511 + j], &sp, &cp);
      } else {  // identity pad pair (elements 1023/1024)
        ct = 1.f; st = 0.f; cp = 0.f; sp = 1.f;
      }
    }
    ((f4*)ws)[tid] = (f4){ct, st, cp, sp};
  } else if (tid < 17408) {
    int i = tid - 16384;
    float sw, cw;
    sincosf(omega[i], &sw, &cw);
    ((f2*)(ws + OMCS_OFF))[i] = (f2){cw, sw};
  }
}

// One wave owns R rows; lane l owns elements 16l..16l+15 (8 even pairs).
// Even rotations register-local; odd rotations register-local except one
// boundary pair per lane (intra-wave shfl). Pipeline: O loads issue before
// even compute; next step's E loads issue after even compute (covered by odd
// compute). Live VGPRs ~ e(64)+E(32)+O(32)+temps — no spill.
template <int R>
__global__ __launch_bounds__(256, 2) void eunn_main(
    const float* __restrict__ x, float* __restrict__ out,
    const float* __restrict__ ws) {
  const int lane = threadIdx.x & 63;
  const int wid = blockIdx.x * (blockDim.x >> 6) + (threadIdx.x >> 6);
  const f4* cf = (const f4*)ws + lane * 8;  // this lane's 8 even pairs, step 0

  // e[r][p] = (re[16l+2p], im[16l+2p], re[16l+2p+1], im[16l+2p+1])
  f4 e[R][8];
#pragma unroll
  for (int r = 0; r < R; ++r) {
    const f4* xr = (const f4*)(x + (size_t)(wid * R + r) * 2048) + lane * 8;
#pragma unroll
    for (int p = 0; p < 8; ++p) e[r][p] = xr[p];
  }

  f4 E[8];  // current step's even coeffs (ct,st,cp,sp per pair)
#pragma unroll
  for (int p = 0; p < 8; ++p) E[p] = cf[p];

#pragma unroll 1
  for (int s = 0; s < 16; ++s) {
    // ---- issue odd coeff loads (completion covered by even compute) ----
    f4 O[8];
    {
      const f4* ob = cf + s * 1024 + 512;
#pragma unroll
      for (int p = 0; p < 8; ++p) O[p] = ob[p];
    }
    // ---- even rotation: pair j=8l+p couples (e.x,e.y) and (e.z,e.w) ----
#pragma unroll
    for (int r = 0; r < R; ++r) {
#pragma unroll
      for (int p = 0; p < 8; ++p) {
        f4 c = E[p];
        f4 v = e[r][p];
        float t0 = c.x * v.x - c.y * v.z;
        float t1 = c.x * v.y - c.y * v.w;
        e[r][p] = (f4){c.w * t0 - c.z * t1, c.z * t0 + c.w * t1,
                       c.y * v.x + c.x * v.z, c.y * v.y + c.x * v.w};
      }
    }
    // ---- load next step's even coeffs into E (covered by odd compute) ----
    {
      const f4* nb = cf + ((s + 1) & 15) * 1024;
#pragma unroll
      for (int p = 0; p < 8; ++p) E[p] = nb[p];
    }
    // ---- odd rotation: pair j couples elements 2j+1, 2j+2 ----
    {
      // neighbor pair (8l-1)'s (ct,st) from lane l-1; identity at lane 0
      float ctm = __shfl_up(O[7].x, 1, 64);
      float stm = __shfl_up(O[7].y, 1, 64);
      if (lane == 0) { ctm = 1.f; stm = 0.f; }
#pragma unroll
      for (int r = 0; r < R; ++r) {
        float upx = __shfl_down(e[r][0].x, 1, 64);  // elem 16l+16 (pre)
        float upy = __shfl_down(e[r][0].y, 1, 64);
        float dnz = __shfl_up(e[r][7].z, 1, 64);    // elem 16l-1 (pre)
        float dnw = __shfl_up(e[r][7].w, 1, 64);
        // element 16l = second half of pair 8l-1
        float nx = stm * dnz + ctm * e[r][0].x;
        float ny = stm * dnw + ctm * e[r][0].y;
        e[r][0].x = nx;
        e[r][0].y = ny;
        // interior odd pairs j=8l+p, p=0..6
#pragma unroll
        for (int p = 0; p < 7; ++p) {
          f4 c = O[p];
          float e0r = e[r][p].z, e0i = e[r][p].w;
          float e1r = e[r][p + 1].x, e1i = e[r][p + 1].y;
          float t0 = c.x * e0r - c.y * e1r;
          float t1 = c.x * e0i - c.y * e1i;
          e[r][p].z = c.w * t0 - c.z * t1;
          e[r][p].w = c.z * t0 + c.w * t1;
          e[r][p + 1].x = c.y * e0r + c.x * e1r;
          e[r][p + 1].y = c.y * e0i + c.x * e1i;
        }
        // boundary pair j=8l+7 (second element lives in lane l+1; lane 63 = identity)
        {
          f4 c = O[7];
          float e0r = e[r][7].z, e0i = e[r][7].w;
          float t0 = c.x * e0r - c.y * upx;
          float t1 = c.x * e0i - c.y * upy;
          e[r][7].z = c.w * t0 - c.z * t1;
          e[r][7].w = c.z * t0 + c.w * t1;
        }
      }
    }
  }

  // ---- final diagonal phase + store ----
  const f4* om4 = (const f4*)(ws + OMCS_OFF) + lane * 8;  // (c,s,c,s)
#pragma unroll
  for (int r = 0; r < R; ++r) {
    f4* outr = (f4*)(out + (size_t)(wid * R + r) * 2048) + lane * 8;
#pragma unroll
    for (int p = 0; p < 8; ++p) {
      f4 v = e[r][p];
      f4 w = om4[p];
      outr[p] = (f4){v.x * w.x - v.y * w.y, v.x * w.y + v.y * w.x,
                     v.z * w.z - v.w * w.w, v.z * w.w + v.w * w.z};
    }
  }
}

extern "C" void kernel_launch(void* const* d_in, const int* in_sizes, int n_in,
                              void* d_out, int out_size, void* d_ws, size_t ws_size,
                              hipStream_t stream) {
  const float* x     = (const float*)d_in[0];  // (4096,1024,2)
  const float* omega = (const float*)d_in[1];  // (1024,)
  const float* et    = (const float*)d_in[2];  // (16,512)
  const float* ot    = (const float*)d_in[3];  // (16,511)
  const float* ep    = (const float*)d_in[4];  // (16,512)
  const float* op    = (const float*)d_in[5];  // (16,511)
  float* out = (float*)d_out;
  float* ws  = (float*)d_ws;

  // 17408 jobs: 16x1024 coeff quads + 1024 omega entries
  eunn_precompute<<<dim3(68), dim3(256), 0, stream>>>(omega, et, ot, ep, op, ws);

  // R=2 rows/wave: 2048 waves, 4 waves/block -> 512 blocks
  eunn_main<2><<<dim3(512), dim3(256), 0, stream>>>(x, out, ws);
}

// Round 4
// 127.724 us; speedup vs baseline: 1.6489x; 1.2416x over previous
//
#include <hip/hip_runtime.h>
#include <math.h>

// EUNN layer, H=1024: 16 steps of (even + odd) pairwise complex rotations + final phase.
// v4 = v3 + TRANSPOSED coefficient layout. v3's loads had lane-stride 128B ->
// each global_load_dwordx4 touched 64 cachelines (~1 line/cyc/CU in TA/L1) ->
// transaction-bound. Transposed layout: slot[p*64+lane] = pair(8*lane+p), so
// each coeff load instruction reads 64 lanes x contiguous 16B = 16 lines (4x fewer).
//
// ws layout (f4 units): coeff_t[s][phase][512], slot k = (j&7)*64 + (j>>3) for pair j
//   (phase 0 = even pairs 0..511; phase 1 = odd pairs 0..510 + identity pad 511)
// omega (f4 = 2 elements (c,s,c,s)) transposed the same way at float offset 65536.

typedef float f4 __attribute__((ext_vector_type(4)));

#define OMCS_OFF 65536

__global__ __launch_bounds__(256) void eunn_precompute(
    const float* __restrict__ omega, const float* __restrict__ et,
    const float* __restrict__ ot, const float* __restrict__ ep,
    const float* __restrict__ op, float* __restrict__ ws) {
  int tid = blockIdx.x * 256 + threadIdx.x;
  if (tid < 16384) {
    int s = tid >> 10, k = tid & 1023;
    int phase = k >> 9, j = k & 511;
    float ct, st, cp, sp;
    if (phase == 0) {
      sincosf(et[s * 512 + j], &st, &ct);
      sincosf(ep[s * 512 + j], &sp, &cp);
    } else if (j < 511) {
      sincosf(ot[s * 511 + j], &st, &ct);
      sincosf(op[s * 511 + j], &sp, &cp);
    } else {  // identity pad pair (elements 1023/1024)
      ct = 1.f; st = 0.f; cp = 0.f; sp = 1.f;
    }
    // transposed slot: lane = j>>3 owns pair j as its (j&7)-th register
    ((f4*)ws)[s * 1024 + phase * 512 + (j & 7) * 64 + (j >> 3)] =
        (f4){ct, st, cp, sp};
  } else if (tid < 16896) {
    int m = tid - 16384;  // f4 index covering elements 2m, 2m+1
    float s0, c0, s1, c1;
    sincosf(omega[2 * m], &s0, &c0);
    sincosf(omega[2 * m + 1], &s1, &c1);
    ((f4*)(ws + OMCS_OFF))[(m & 7) * 64 + (m >> 3)] = (f4){c0, s0, c1, s1};
  }
}

// One wave owns R rows; lane l owns elements 16l..16l+15 (8 even pairs).
// Even rotations register-local; odd rotations register-local except one
// boundary pair per lane (intra-wave shfl). Pipeline: O loads issue before
// even compute; next step's E loads issue after even compute.
template <int R>
__global__ __launch_bounds__(256, 2) void eunn_main(
    const float* __restrict__ x, float* __restrict__ out,
    const float* __restrict__ ws) {
  const int lane = threadIdx.x & 63;
  const int wid = blockIdx.x * (blockDim.x >> 6) + (threadIdx.x >> 6);
  const f4* cf = (const f4*)ws + lane;  // + p*64 + s*1024 (+512 for odd)

  // e[r][p] = (re[16l+2p], im[16l+2p], re[16l+2p+1], im[16l+2p+1])
  f4 e[R][8];
#pragma unroll
  for (int r = 0; r < R; ++r) {
    const f4* xr = (const f4*)(x + (size_t)(wid * R + r) * 2048) + lane * 8;
#pragma unroll
    for (int p = 0; p < 8; ++p) e[r][p] = xr[p];
  }

  f4 E[8];  // current step's even coeffs (ct,st,cp,sp per pair)
#pragma unroll
  for (int p = 0; p < 8; ++p) E[p] = cf[p * 64];

#pragma unroll 1
  for (int s = 0; s < 16; ++s) {
    // ---- issue odd coeff loads (completion covered by even compute) ----
    f4 O[8];
    {
      const f4* ob = cf + s * 1024 + 512;
#pragma unroll
      for (int p = 0; p < 8; ++p) O[p] = ob[p * 64];
    }
    // ---- even rotation: pair j=8l+p couples (e.x,e.y) and (e.z,e.w) ----
#pragma unroll
    for (int r = 0; r < R; ++r) {
#pragma unroll
      for (int p = 0; p < 8; ++p) {
        f4 c = E[p];
        f4 v = e[r][p];
        float t0 = c.x * v.x - c.y * v.z;
        float t1 = c.x * v.y - c.y * v.w;
        e[r][p] = (f4){c.w * t0 - c.z * t1, c.z * t0 + c.w * t1,
                       c.y * v.x + c.x * v.z, c.y * v.y + c.x * v.w};
      }
    }
    // ---- load next step's even coeffs into E (covered by odd compute) ----
    {
      const f4* nb = cf + ((s + 1) & 15) * 1024;
#pragma unroll
      for (int p = 0; p < 8; ++p) E[p] = nb[p * 64];
    }
    // ---- odd rotation: pair j couples elements 2j+1, 2j+2 ----
    {
      // neighbor pair (8l-1)'s (ct,st) from lane l-1; identity at lane 0
      float ctm = __shfl_up(O[7].x, 1, 64);
      float stm = __shfl_up(O[7].y, 1, 64);
      if (lane == 0) { ctm = 1.f; stm = 0.f; }
#pragma unroll
      for (int r = 0; r < R; ++r) {
        float upx = __shfl_down(e[r][0].x, 1, 64);  // elem 16l+16 (pre)
        float upy = __shfl_down(e[r][0].y, 1, 64);
        float dnz = __shfl_up(e[r][7].z, 1, 64);    // elem 16l-1 (pre)
        float dnw = __shfl_up(e[r][7].w, 1, 64);
        // element 16l = second half of pair 8l-1
        float nx = stm * dnz + ctm * e[r][0].x;
        float ny = stm * dnw + ctm * e[r][0].y;
        e[r][0].x = nx;
        e[r][0].y = ny;
        // interior odd pairs j=8l+p, p=0..6
#pragma unroll
        for (int p = 0; p < 7; ++p) {
          f4 c = O[p];
          float e0r = e[r][p].z, e0i = e[r][p].w;
          float e1r = e[r][p + 1].x, e1i = e[r][p + 1].y;
          float t0 = c.x * e0r - c.y * e1r;
          float t1 = c.x * e0i - c.y * e1i;
          e[r][p].z = c.w * t0 - c.z * t1;
          e[r][p].w = c.z * t0 + c.w * t1;
          e[r][p + 1].x = c.y * e0r + c.x * e1r;
          e[r][p + 1].y = c.y * e0i + c.x * e1i;
        }
        // boundary pair j=8l+7 (second element lives in lane l+1; lane 63 = identity)
        {
          f4 c = O[7];
          float e0r = e[r][7].z, e0i = e[r][7].w;
          float t0 = c.x * e0r - c.y * upx;
          float t1 = c.x * e0i - c.y * upy;
          e[r][7].z = c.w * t0 - c.z * t1;
          e[r][7].w = c.z * t0 + c.w * t1;
        }
      }
    }
  }

  // ---- final diagonal phase + store ----
  const f4* om4 = (const f4*)(ws + OMCS_OFF) + lane;  // (c,s,c,s), + p*64
#pragma unroll
  for (int r = 0; r < R; ++r) {
    f4* outr = (f4*)(out + (size_t)(wid * R + r) * 2048) + lane * 8;
#pragma unroll
    for (int p = 0; p < 8; ++p) {
      f4 v = e[r][p];
      f4 w = om4[p * 64];
      outr[p] = (f4){v.x * w.x - v.y * w.y, v.x * w.y + v.y * w.x,
                     v.z * w.z - v.w * w.w, v.z * w.w + v.w * w.z};
    }
  }
}

extern "C" void kernel_launch(void* const* d_in, const int* in_sizes, int n_in,
                              void* d_out, int out_size, void* d_ws, size_t ws_size,
                              hipStream_t stream) {
  const float* x     = (const float*)d_in[0];  // (4096,1024,2)
  const float* omega = (const float*)d_in[1];  // (1024,)
  const float* et    = (const float*)d_in[2];  // (16,512)
  const float* ot    = (const float*)d_in[3];  // (16,511)
  const float* ep    = (const float*)d_in[4];  // (16,512)
  const float* op    = (const float*)d_in[5];  // (16,511)
  float* out = (float*)d_out;
  float* ws  = (float*)d_ws;

  // 16896 jobs: 16x1024 coeff quads + 512 omega f4 entries
  eunn_precompute<<<dim3(66), dim3(256), 0, stream>>>(omega, et, ot, ep, op, ws);

  // R=2 rows/wave: 2048 waves, 4 waves/block -> 512 blocks
  eunn_main<2><<<dim3(512), dim3(256), 0, stream>>>(x, out, ws);
}